// Round 5
// baseline (3791.623 us; speedup 1.0000x reference)
//
#include <hip/hip_runtime.h>
#include <cstdint>
#include <cstddef>

#define DI __device__ __forceinline__

typedef __bf16 bf16_t;
typedef __bf16 bf16x8 __attribute__((ext_vector_type(8)));
typedef float f32x4 __attribute__((ext_vector_type(4)));

static constexpr float SCALE = 0.17677669529663687f;  // 32^-0.5

DI bf16_t f2b(float f) {
  uint32_t u = __builtin_bit_cast(uint32_t, f);
  u += 0x7fffu + ((u >> 16) & 1u);
  return __builtin_bit_cast(bf16_t, (uint16_t)(u >> 16));
}

// ---------------- weight convert f32 -> bf16 ----------------
__global__ __launch_bounds__(256)
void cvtw(const float* __restrict__ in, bf16_t* __restrict__ out, int n) {
  int i = (blockIdx.x * 256 + threadIdx.x) * 4;
  if (i >= n) return;
  float4 v = *(const float4*)(in + i);
  ushort4 o;
  o.x = __builtin_bit_cast(uint16_t, f2b(v.x));
  o.y = __builtin_bit_cast(uint16_t, f2b(v.y));
  o.z = __builtin_bit_cast(uint16_t, f2b(v.z));
  o.w = __builtin_bit_cast(uint16_t, f2b(v.w));
  *(ushort4*)(out + i) = o;
}

// ---------------- rel-pos bias expand: [16][64][64], pad = -1e30 ----------------
__global__ __launch_bounds__(256)
void bias_pre(const float* __restrict__ rel, float* __restrict__ bf) {
  int idx = blockIdx.x * 256 + threadIdx.x;  // 65536
  int head = idx >> 12, t1 = (idx >> 6) & 63, t2 = idx & 63;
  float v = -1e30f;
  if (t1 < 49 && t2 < 49) {
    int i1 = t1 / 7, j1 = t1 - i1 * 7, i2 = t2 / 7, j2 = t2 - i2 * 7;
    v = rel[((i1 - i2 + 6) * 13 + (j1 - j2 + 6)) * 16 + head];
  }
  bf[idx] = v;
}

// ---------------- LayerNorm (+optional shift+window gather) ----------------
template<bool WIN>
__global__ __launch_bounds__(128)
void ln_kernel(const float* __restrict__ in, const float* __restrict__ g,
               const float* __restrict__ be, bf16_t* __restrict__ out)
{
  const int r = blockIdx.x;           // output row (windowed if WIN)
  const int tid = threadIdx.x;
  long srow;
  if (WIN) {
    int bw = r / 49, t = r - bw * 49;
    int b = bw >> 6, w = bw & 63;
    int wh = w >> 3, ww = w & 7;
    int i = t / 7, j = t - i * 7;
    int hs = wh * 7 + i + 3; if (hs >= 56) hs -= 56;
    int wsr = ww * 7 + j + 3; if (wsr >= 56) wsr -= 56;
    srow = (long)b * 3136 + hs * 56 + wsr;
  } else {
    srow = r;
  }
  const float4 v = *(const float4*)(in + srow * 512 + tid * 4);
  float s = v.x + v.y + v.z + v.w;
  float sq = v.x * v.x + v.y * v.y + v.z * v.z + v.w * v.w;
#pragma unroll
  for (int m = 1; m < 64; m <<= 1) { s += __shfl_xor(s, m); sq += __shfl_xor(sq, m); }
  __shared__ float ls[2], lq[2];
  if ((tid & 63) == 0) { ls[tid >> 6] = s; lq[tid >> 6] = sq; }
  __syncthreads();
  s = ls[0] + ls[1]; sq = lq[0] + lq[1];
  const float mean = s * (1.f / 512.f);
  const float rs = rsqrtf(sq * (1.f / 512.f) - mean * mean + 1e-5f);
  const float4 gg = *(const float4*)(g + tid * 4);
  const float4 bb = *(const float4*)(be + tid * 4);
  ushort4 o;
  o.x = __builtin_bit_cast(uint16_t, f2b((v.x - mean) * rs * gg.x + bb.x));
  o.y = __builtin_bit_cast(uint16_t, f2b((v.y - mean) * rs * gg.y + bb.y));
  o.z = __builtin_bit_cast(uint16_t, f2b((v.z - mean) * rs * gg.z + bb.z));
  o.w = __builtin_bit_cast(uint16_t, f2b((v.w - mean) * rs * gg.w + bb.w));
  *(ushort4*)(out + (long)r * 512 + tid * 4) = o;
}

#define MFMA16(a, b, c) __builtin_amdgcn_mfma_f32_16x16x32_bf16((a), (b), (c), 0, 0, 0)

// Common epilogue address/value logic
template<int EPI>
DI void epi_store(int grow, int gcol, float v, const float* extra,
                  void* out0, void* out1v, void* out2v)
{
  long obase = 0;
  if (EPI == 0) {
    int bwi = grow / 49, t_ = grow - bwi * 49;
    obase = ((long)bwi * 784 + t_) * 32;
  } else if (EPI == 1) {
    int bwi = grow / 49, t_ = grow - bwi * 49;
    int b = bwi >> 6, w = bwi & 63;
    int wh = w >> 3, ww = w & 7;
    int i = t_ / 7, jj = t_ - i * 7;
    int hs = wh * 7 + i + 3; if (hs >= 56) hs -= 56;
    int wsr = ww * 7 + jj + 3; if (wsr >= 56) wsr -= 56;
    obase = ((long)b * 3136 + hs * 56 + wsr) * 512;
  } else if (EPI == 2) {
    obase = (long)grow * 2048;
  } else {
    obase = (long)grow * 512;
  }
  if (EPI == 0) {
    int part = gcol >> 9, head = (gcol >> 5) & 15, d = gcol & 31;
    if (part == 0) v *= SCALE;
    bf16_t* dst = (bf16_t*)(part == 0 ? out0 : (part == 1 ? out1v : out2v));
    dst[obase + (long)head * 1568 + d] = f2b(v);
  } else if (EPI == 1) {
    ((float*)out0)[obase + gcol] = v + extra[obase + gcol];
  } else if (EPI == 2) {
    float m2 = v * v;
    float z = v * fmaf(0.07135481627f, m2, 1.59576912161f);
    float e = __expf(z);
    float rr = __builtin_amdgcn_rcpf(e + 1.0f);
    ((bf16_t*)out0)[obase + gcol] = f2b(fmaf(-v, rr, v));
  } else {
    ((float*)out0)[obase + gcol] = v + extra[obase + gcol];
  }
}

// ---------------- gemmR: K=512, B-panel LDS-resident, deep A reg-queue -------
// C[M,N] = A[M,K]*Bw[N,K]^T, M=100352 (392 bm-tiles), tile 256x128, BK=32.
// 1024 thr = 16 waves (8M x 2N), wave 32x64, acc[2][4].
// LDS: B resident as 16 k-major regions [128][32] (128 KB; k-major keeps row
// stride 64B -> same proven conflict-free XOR addressing) + A dbuf 2x16 KB.
// A stream: per-thread dwordx4 into reg queue aq[8]; loads for step s+8 issue
// at step s; vmcnt(7) forces ONLY pair s+1 (7 steps of slack; 7x16KB=112KB in
// flight/CU) then ds_write into Alds[(s+1)&1].  ONE barrier per step.
// Walk: fixed bn = j%NBN, bm = j/NBN + k*(256/NBN)  (global; L3 shares panels).
template<int EPI, int NBN>
__global__ __launch_bounds__(1024, 4)
void gemmR(const bf16_t* __restrict__ A, const bf16_t* __restrict__ Bw,
           const float* __restrict__ bias, const float* __restrict__ extra,
           void* __restrict__ out0, void* __restrict__ out1v, void* __restrict__ out2v)
{
  constexpr int K = 512;
  __shared__ __align__(128) bf16_t Alds[2][8192];
  __shared__ __align__(128) bf16_t Blds[16][4096];
  const int tid = threadIdx.x, lane = tid & 63, wave = tid >> 6;
  const int nWalk = 256 / NBN;
  const int j = blockIdx.x;
  if (j >= nWalk * NBN) return;
  const int bn = j % NBN;
  const int bm0 = j / NBN;
  const int tiles = (392 - bm0 + nWalk - 1) / nWalk;

  // ---- B prologue: resident panel, 128 KB ----
  {
    const int prow = tid >> 3, ps8 = tid & 7;
    const bf16_t* bsrc = Bw + (size_t)(bn * 128 + prow) * K + ps8 * 4;
    const int wslot = (((ps8 >> 1) ^ ((prow >> 1) & 3)) << 4) + (ps8 & 1) * 8;
    uint2 tmp[16];
#pragma unroll
    for (int r = 0; r < 16; ++r) tmp[r] = *(const uint2*)(bsrc + r * 32);
#pragma unroll
    for (int r = 0; r < 16; ++r)
      *(uint2*)((char*)&Blds[r][0] + prow * 64 + wslot) = tmp[r];
  }
  asm volatile("s_waitcnt vmcnt(0)");   // clean vmcnt slate for queue counting

  // ---- A staging geometry ----
  const int srow = tid >> 2, slot = tid & 3;
  const int wby = srow * 64 + (((slot ^ ((srow >> 1) & 3))) << 4);
  const bf16_t* pAs = A + (size_t)(bm0 * 256 + srow) * K + slot * 8;
  int ktS = 0, bmS = bm0;
  uint4 aq[8];

#define ADV() do { \
    if (++ktS == 16) { ktS = 0; bmS += nWalk; if (bmS < 392) pAs += (size_t)nWalk * 131072; } \
  } while (0)
#define LOADQ(U) do { aq[U] = *(const uint4*)(pAs + ktS * 32); ADV(); } while (0)

  // fragment addressing (proven scheme): chunk fkc of row R at slot fkc^((R>>1)&3)
  const int fr = lane & 15, fkc = lane >> 4;
  const int wr = wave >> 1, wc = wave & 1;
  const int slotq = (fkc ^ ((fr >> 1) & 3)) << 3;
  const int aoff = (wr * 32 + fr) * 32 + slotq;   // + m*512
  const int boff = (wc * 64 + fr) * 32 + slotq;   // + n*512

  f32x4 acc[2][4] = {};

  // ---- prologue: fill queue (steps 0..7), commit step 0 ----
  LOADQ(0); LOADQ(1); LOADQ(2); LOADQ(3); LOADQ(4); LOADQ(5); LOADQ(6); LOADQ(7);
  asm volatile("s_waitcnt vmcnt(7)");
  __builtin_amdgcn_sched_barrier(0);
  *(uint4*)((char*)&Alds[0][0] + wby) = aq[0];
  asm volatile("s_waitcnt lgkmcnt(0)");
  __builtin_amdgcn_s_barrier();
  __builtin_amdgcn_sched_barrier(0);

  const int rq = fkc * 4;
  float bs[4];
#pragma unroll
  for (int n = 0; n < 4; ++n) bs[n] = bias[bn * 128 + wc * 64 + n * 16 + fr];

  for (int t = 0; t < tiles; ++t) {
#pragma unroll
    for (int kt = 0; kt < 16; ++kt) {
      const int u = kt & 7;
      bf16x8 af0 = *(const bf16x8*)&Alds[kt & 1][aoff];
      bf16x8 af1 = *(const bf16x8*)&Alds[kt & 1][aoff + 512];
      bf16x8 b0 = *(const bf16x8*)&Blds[kt][boff];
      bf16x8 b1 = *(const bf16x8*)&Blds[kt][boff + 512];
      bf16x8 b2 = *(const bf16x8*)&Blds[kt][boff + 1024];
      bf16x8 b3 = *(const bf16x8*)&Blds[kt][boff + 1536];
      LOADQ(u);                       // pair s+8 into freed slot
      asm volatile("s_waitcnt lgkmcnt(0)");
      __builtin_amdgcn_sched_barrier(0);
      __builtin_amdgcn_s_setprio(1);
      acc[0][0] = MFMA16(af0, b0, acc[0][0]);
      acc[0][1] = MFMA16(af0, b1, acc[0][1]);
      acc[0][2] = MFMA16(af0, b2, acc[0][2]);
      acc[0][3] = MFMA16(af0, b3, acc[0][3]);
      acc[1][0] = MFMA16(af1, b0, acc[1][0]);
      acc[1][1] = MFMA16(af1, b1, acc[1][1]);
      acc[1][2] = MFMA16(af1, b2, acc[1][2]);
      acc[1][3] = MFMA16(af1, b3, acc[1][3]);
      __builtin_amdgcn_s_setprio(0);
      __builtin_amdgcn_sched_barrier(0);
      asm volatile("s_waitcnt vmcnt(7)");    // pair s+1 (7 steps old) landed
      __builtin_amdgcn_sched_barrier(0);
      *(uint4*)((char*)&Alds[(kt + 1) & 1][0] + wby) = aq[(u + 1) & 7];
      asm volatile("s_waitcnt lgkmcnt(0)");
      __builtin_amdgcn_s_barrier();
      __builtin_amdgcn_sched_barrier(0);
    }
    // ---- per-tile epilogue (queue keeps flying; vmem here only tightens waits)
    const int bmC = bm0 + t * nWalk;
#pragma unroll
    for (int m = 0; m < 2; ++m)
#pragma unroll
      for (int jj = 0; jj < 4; ++jj) {
        const int grow = bmC * 256 + wr * 32 + m * 16 + rq + jj;
#pragma unroll
        for (int n = 0; n < 4; ++n) {
          const int gcol = bn * 128 + wc * 64 + n * 16 + fr;
          epi_store<EPI>(grow, gcol, acc[m][n][jj] + bs[n], extra, out0, out1v, out2v);
        }
      }
#pragma unroll
    for (int m = 0; m < 2; ++m)
#pragma unroll
      for (int n = 0; n < 4; ++n) acc[m][n] = (f32x4){0.f, 0.f, 0.f, 0.f};
  }
#undef LOADQ
#undef ADV
}

// ---------------- gemmS: K=2048 (MLP2), dual deep reg-queue ------------------
// tile 256x128, BK=32, 512 thr = 8 waves (4M x 2N), wave 64x64, acc[4][4].
// LDS: A dbuf 2x16 KB + B dbuf 2x8 KB = 48 KB.  Queue D=8 on BOTH streams
// (3 ops/step: 2xA dwordx4 + 1xB dwordx4); vmcnt(21) forces only triple s+1
// (7 steps slack, 7x24KB=168KB in flight/CU).  ~200 VGPR @ 2 waves/SIMD.
__global__ __launch_bounds__(512, 2)
void gemmS(const bf16_t* __restrict__ A, const bf16_t* __restrict__ Bw,
           const float* __restrict__ bias, const float* __restrict__ extra,
           void* __restrict__ out0)
{
  constexpr int K = 2048, NBN = 4, nWalk = 64;
  __shared__ __align__(128) bf16_t Alds[2][8192];
  __shared__ __align__(128) bf16_t Blds2[2][4096];
  const int tid = threadIdx.x, lane = tid & 63, wave = tid >> 6;
  const int j = blockIdx.x;
  const int bn = j % NBN;
  const int bm0 = j / NBN;
  const int tiles = (392 - bm0 + nWalk - 1) / nWalk;

  // staging geometry
  const int srow2 = tid >> 1, s0 = (tid & 1) * 2;           // A: 32 B/thread
  const int brow = tid >> 2, bslot = tid & 3;               // B: 16 B/thread
  const bf16_t* pA0 = A + (size_t)(bm0 * 256 + srow2) * K + s0 * 8;
  const bf16_t* pB0 = Bw + (size_t)(bn * 128 + brow) * K + bslot * 8;
  const int wbyA0 = srow2 * 64 + ((s0 ^ ((srow2 >> 1) & 3)) << 4);
  const int wbyA1 = srow2 * 64 + (((s0 + 1) ^ ((srow2 >> 1) & 3)) << 4);
  const int wbyB = brow * 64 + ((bslot ^ ((brow >> 1) & 3)) << 4);
  int ktS = 0, bmS = bm0;
  uint4 aqA0[8], aqA1[8], aqB[8];

#define ADVS() do { \
    if (++ktS == 64) { ktS = 0; bmS += nWalk; if (bmS < 392) pA0 += (size_t)nWalk * 524288; } \
  } while (0)
#define LOADQS(U) do { \
    aqA0[U] = *(const uint4*)(pA0 + ktS * 32); \
    aqA1[U] = *(const uint4*)(pA0 + ktS * 32 + 8); \
    aqB[U]  = *(const uint4*)(pB0 + ktS * 32); \
    ADVS(); \
  } while (0)

  const int fr = lane & 15, fkc = lane >> 4;
  const int wr = wave >> 1, wc = wave & 1;
  const int slotq = (fkc ^ ((fr >> 1) & 3)) << 3;
  const int aoff = (wr * 64 + fr) * 32 + slotq;   // + m*512
  const int boff = (wc * 64 + fr) * 32 + slotq;   // + n*512

  f32x4 acc[4][4] = {};

  LOADQS(0); LOADQS(1); LOADQS(2); LOADQS(3);
  LOADQS(4); LOADQS(5); LOADQS(6); LOADQS(7);
  asm volatile("s_waitcnt vmcnt(21)");
  __builtin_amdgcn_sched_barrier(0);
  *(uint4*)((char*)&Alds[0][0] + wbyA0) = aqA0[0];
  *(uint4*)((char*)&Alds[0][0] + wbyA1) = aqA1[0];
  *(uint4*)((char*)&Blds2[0][0] + wbyB) = aqB[0];
  asm volatile("s_waitcnt lgkmcnt(0)");
  __builtin_amdgcn_s_barrier();
  __builtin_amdgcn_sched_barrier(0);

  const int rq = fkc * 4;
  float bs[4];
#pragma unroll
  for (int n = 0; n < 4; ++n) bs[n] = bias[bn * 128 + wc * 64 + n * 16 + fr];

  for (int t = 0; t < tiles; ++t) {
#pragma unroll 1
    for (int g = 0; g < 8; ++g) {
#pragma unroll
      for (int u = 0; u < 8; ++u) {
        const int par = u & 1;   // (g*8+u)&1
        bf16x8 af0 = *(const bf16x8*)&Alds[par][aoff];
        bf16x8 af1 = *(const bf16x8*)&Alds[par][aoff + 512];
        bf16x8 af2 = *(const bf16x8*)&Alds[par][aoff + 1024];
        bf16x8 af3 = *(const bf16x8*)&Alds[par][aoff + 1536];
        bf16x8 b0 = *(const bf16x8*)&Blds2[par][boff];
        bf16x8 b1 = *(const bf16x8*)&Blds2[par][boff + 512];
        bf16x8 b2 = *(const bf16x8*)&Blds2[par][boff + 1024];
        bf16x8 b3 = *(const bf16x8*)&Blds2[par][boff + 1536];
        LOADQS(u);
        asm volatile("s_waitcnt lgkmcnt(0)");
        __builtin_amdgcn_sched_barrier(0);
        __builtin_amdgcn_s_setprio(1);
        acc[0][0] = MFMA16(af0, b0, acc[0][0]);
        acc[0][1] = MFMA16(af0, b1, acc[0][1]);
        acc[0][2] = MFMA16(af0, b2, acc[0][2]);
        acc[0][3] = MFMA16(af0, b3, acc[0][3]);
        acc[1][0] = MFMA16(af1, b0, acc[1][0]);
        acc[1][1] = MFMA16(af1, b1, acc[1][1]);
        acc[1][2] = MFMA16(af1, b2, acc[1][2]);
        acc[1][3] = MFMA16(af1, b3, acc[1][3]);
        acc[2][0] = MFMA16(af2, b0, acc[2][0]);
        acc[2][1] = MFMA16(af2, b1, acc[2][1]);
        acc[2][2] = MFMA16(af2, b2, acc[2][2]);
        acc[2][3] = MFMA16(af2, b3, acc[2][3]);
        acc[3][0] = MFMA16(af3, b0, acc[3][0]);
        acc[3][1] = MFMA16(af3, b1, acc[3][1]);
        acc[3][2] = MFMA16(af3, b2, acc[3][2]);
        acc[3][3] = MFMA16(af3, b3, acc[3][3]);
        __builtin_amdgcn_s_setprio(0);
        __builtin_amdgcn_sched_barrier(0);
        asm volatile("s_waitcnt vmcnt(21)");   // triple s+1 landed
        __builtin_amdgcn_sched_barrier(0);
        *(uint4*)((char*)&Alds[par ^ 1][0] + wbyA0) = aqA0[(u + 1) & 7];
        *(uint4*)((char*)&Alds[par ^ 1][0] + wbyA1) = aqA1[(u + 1) & 7];
        *(uint4*)((char*)&Blds2[par ^ 1][0] + wbyB) = aqB[(u + 1) & 7];
        asm volatile("s_waitcnt lgkmcnt(0)");
        __builtin_amdgcn_s_barrier();
        __builtin_amdgcn_sched_barrier(0);
      }
    }
    const int bmC = bm0 + t * nWalk;
#pragma unroll
    for (int m = 0; m < 4; ++m)
#pragma unroll
      for (int jj = 0; jj < 4; ++jj) {
        const int grow = bmC * 256 + wr * 64 + m * 16 + rq + jj;
#pragma unroll
        for (int n = 0; n < 4; ++n) {
          const int gcol = bn * 128 + wc * 64 + n * 16 + fr;
          epi_store<3>(grow, gcol, acc[m][n][jj] + bs[n], extra, out0, nullptr, nullptr);
        }
      }
#pragma unroll
    for (int m = 0; m < 4; ++m)
#pragma unroll
      for (int n = 0; n < 4; ++n) acc[m][n] = (f32x4){0.f, 0.f, 0.f, 0.f};
  }
#undef LOADQS
#undef ADVS
}

// ---------------- attention: one block per (window, head) ----------------
__global__ __launch_bounds__(256)
void attn_kernel(const bf16_t* __restrict__ qb, const bf16_t* __restrict__ kb,
                 const bf16_t* __restrict__ vb, const float* __restrict__ biasf,
                 bf16_t* __restrict__ aout)
{
  __shared__ bf16_t Q[64 * 32];
  __shared__ bf16_t Kl[64 * 32];
  __shared__ bf16_t Vt[32 * 64];
  __shared__ bf16_t Pl[4][16 * 64];
  const int bid = blockIdx.x;
  const int bw = bid >> 4, head = bid & 15;
  const int tid = threadIdx.x, lane = tid & 63, wave = tid >> 6;
  {
    uint4 z = {0u, 0u, 0u, 0u};
    *(uint4*)&Q[tid * 8] = z;
    *(uint4*)&Kl[tid * 8] = z;
    *(uint4*)&Vt[tid * 8] = z;
  }
  __syncthreads();
  const bf16_t* qsrc = qb + (long)bid * (49 * 32);
  const bf16_t* ksrc = kb + (long)bid * (49 * 32);
  const bf16_t* vsrc = vb + (long)bid * (49 * 32);
  if (tid < 196) {
    *(uint4*)&Q[tid * 8] = *(const uint4*)(qsrc + tid * 8);
    *(uint4*)&Kl[tid * 8] = *(const uint4*)(ksrc + tid * 8);
  }
  for (int e = tid; e < 1568; e += 256) {
    int t = e >> 5, d = e & 31;
    Vt[d * 64 + t] = vsrc[e];
  }
  __syncthreads();
  const int fr = lane & 15, fk = (lane >> 4) * 8, rq = (lane >> 4) * 4;
  bf16x8 aq = *(const bf16x8*)&Q[(wave * 16 + fr) * 32 + fk];
  f32x4 s[4];
#pragma unroll
  for (int n = 0; n < 4; ++n) {
    bf16x8 bk = *(const bf16x8*)&Kl[(n * 16 + fr) * 32 + fk];
    f32x4 z = {0.f, 0.f, 0.f, 0.f};
    s[n] = __builtin_amdgcn_mfma_f32_16x16x32_bf16(aq, bk, z, 0, 0, 0);
  }
  const int w = bw & 63;
  const bool wh7 = ((w >> 3) == 7), ww7 = ((w & 7) == 7);
  const float* bh = biasf + head * 4096;
#pragma unroll
  for (int j = 0; j < 4; ++j) {
    const int row = wave * 16 + rq + j;  // t1 in [0,64)
    int i1 = row / 7, j1 = row - i1 * 7;
    bool b1h = wh7 && (i1 >= 4), b1w = ww7 && (j1 >= 4);
    float pv[4];
    float mx = -3.0e38f;
#pragma unroll
    for (int n = 0; n < 4; ++n) {
      const int col = n * 16 + fr;
      float v = s[n][j] + bh[row * 64 + col];
      if (wh7 || ww7) {
        int i2 = col / 7, j2 = col - i2 * 7;
        bool b2h = wh7 && (i2 >= 4), b2w = ww7 && (j2 >= 4);
        if ((b1h != b2h) || (b1w != b2w)) v -= 100.f;
      }
      pv[n] = v;
      mx = fmaxf(mx, v);
    }
#pragma unroll
    for (int msk = 1; msk < 16; msk <<= 1) mx = fmaxf(mx, __shfl_xor(mx, msk));
    float sm = 0.f;
#pragma unroll
    for (int n = 0; n < 4; ++n) { pv[n] = __expf(pv[n] - mx); sm += pv[n]; }
#pragma unroll
    for (int msk = 1; msk < 16; msk <<= 1) sm += __shfl_xor(sm, msk);
    const float inv = 1.f / sm;
#pragma unroll
    for (int n = 0; n < 4; ++n)
      Pl[wave][(rq + j) * 64 + n * 16 + fr] = f2b(pv[n] * inv);
  }
  __syncthreads();
  f32x4 o[2] = {};
#pragma unroll
  for (int kk = 0; kk < 2; ++kk) {
    bf16x8 pa = *(const bf16x8*)&Pl[wave][fr * 64 + kk * 32 + fk];
#pragma unroll
    for (int dt = 0; dt < 2; ++dt) {
      bf16x8 vv = *(const bf16x8*)&Vt[(dt * 16 + fr) * 64 + kk * 32 + fk];
      o[dt] = __builtin_amdgcn_mfma_f32_16x16x32_bf16(pa, vv, o[dt], 0, 0, 0);
    }
  }
#pragma unroll
  for (int j = 0; j < 4; ++j) {
    const int t1 = wave * 16 + rq + j;
    if (t1 < 49) {
      bf16_t* dst = aout + ((long)bw * 49 + t1) * 512 + head * 32;
      dst[fr] = f2b(o[0][j]);
      dst[16 + fr] = f2b(o[1][j]);
    }
  }
}

// ---------------- launch ----------------
extern "C" void kernel_launch(void* const* d_in, const int* in_sizes, int n_in,
                              void* d_out, int out_size, void* d_ws, size_t ws_size,
                              hipStream_t stream)
{
  const float* x      = (const float*)d_in[0];
  const float* n1g    = (const float*)d_in[1];
  const float* n1b    = (const float*)d_in[2];
  const float* qkv_w  = (const float*)d_in[3];
  const float* qkv_b  = (const float*)d_in[4];
  const float* rel    = (const float*)d_in[5];
  const float* proj_w = (const float*)d_in[6];
  const float* proj_b = (const float*)d_in[7];
  const float* n2g    = (const float*)d_in[8];
  const float* n2b    = (const float*)d_in[9];
  const float* w1     = (const float*)d_in[10];
  const float* b1     = (const float*)d_in[11];
  const float* w2     = (const float*)d_in[12];
  const float* b2     = (const float*)d_in[13];

  char* ws = (char*)d_ws;
  bf16_t* Wqkv  = (bf16_t*)(ws + 0);          // 1536*512*2 = 1572864
  bf16_t* Wproj = (bf16_t*)(ws + 1572864);    // 512*512*2  = 524288
  bf16_t* Wm1   = (bf16_t*)(ws + 2097152);    // 2048*512*2 = 2097152
  bf16_t* Wm2   = (bf16_t*)(ws + 4194304);    // 512*2048*2 = 2097152
  float*  biasf = (float*)(ws + 6291456);     // 16*64*64*4 = 1048576
  const size_t ABYTES = (size_t)100352 * 512 * 2;  // 102760448
  const size_t P1 = 8388608;
  const size_t P2 = P1 + ABYTES + 1048576;         // 112197632
  bf16_t* xw      = (bf16_t*)(ws + P1);
  bf16_t* qbuf    = (bf16_t*)(ws + P2);
  bf16_t* kbuf    = (bf16_t*)(ws + P2 + ABYTES);
  bf16_t* vbuf    = (bf16_t*)(ws + P2 + 2 * ABYTES);
  bf16_t* attnout = xw;       // reuse after QKV gemm consumed xw
  bf16_t* h2      = xw;       // reuse after proj consumed attnout
  bf16_t* hidden  = qbuf;     // reuse q/k/v (+spare) after attention

  cvtw<<<768, 256, 0, stream>>>(qkv_w, Wqkv, 1536 * 512);
  cvtw<<<256, 256, 0, stream>>>(proj_w, Wproj, 512 * 512);
  cvtw<<<1024, 256, 0, stream>>>(w1, Wm1, 2048 * 512);
  cvtw<<<1024, 256, 0, stream>>>(w2, Wm2, 512 * 2048);
  bias_pre<<<256, 256, 0, stream>>>(rel, biasf);

  ln_kernel<true><<<100352, 128, 0, stream>>>(x, n1g, n1b, xw);
  gemmR<0, 12><<<256, 1024, 0, stream>>>(xw, Wqkv, qkv_b, nullptr, qbuf, kbuf, vbuf);
  attn_kernel<<<32768, 256, 0, stream>>>(qbuf, kbuf, vbuf, biasf, attnout);
  gemmR<1, 4><<<256, 1024, 0, stream>>>(attnout, Wproj, proj_b, x, d_out, nullptr, nullptr);
  ln_kernel<false><<<100352, 128, 0, stream>>>((const float*)d_out, n2g, n2b, h2);
  gemmR<2, 16><<<256, 1024, 0, stream>>>(h2, Wm1, b1, nullptr, hidden, nullptr, nullptr);
  gemmS<<<256, 512, 0, stream>>>(hidden, Wm2, b2, (const float*)d_out, d_out);
}

// Round 6
// 1376.789 us; speedup vs baseline: 2.7540x; 2.7540x over previous
//
#include <hip/hip_runtime.h>
#include <cstdint>
#include <cstddef>

#define DI __device__ __forceinline__

typedef __bf16 bf16_t;
typedef __bf16 bf16x8 __attribute__((ext_vector_type(8)));
typedef float f32x4 __attribute__((ext_vector_type(4)));

static constexpr float SCALE = 0.17677669529663687f;  // 32^-0.5

DI bf16_t f2b(float f) {
  uint32_t u = __builtin_bit_cast(uint32_t, f);
  u += 0x7fffu + ((u >> 16) & 1u);
  return __builtin_bit_cast(bf16_t, (uint16_t)(u >> 16));
}

DI void gld16(const void* g, void* l) {
  __builtin_amdgcn_global_load_lds(
      (const __attribute__((address_space(1))) uint32_t*)g,
      (__attribute__((address_space(3))) uint32_t*)l, 16, 0, 0);
}

// ---------------- weight convert f32 -> bf16 ----------------
__global__ __launch_bounds__(256)
void cvtw(const float* __restrict__ in, bf16_t* __restrict__ out, int n) {
  int i = (blockIdx.x * 256 + threadIdx.x) * 4;
  if (i >= n) return;
  float4 v = *(const float4*)(in + i);
  ushort4 o;
  o.x = __builtin_bit_cast(uint16_t, f2b(v.x));
  o.y = __builtin_bit_cast(uint16_t, f2b(v.y));
  o.z = __builtin_bit_cast(uint16_t, f2b(v.z));
  o.w = __builtin_bit_cast(uint16_t, f2b(v.w));
  *(ushort4*)(out + i) = o;
}

// ---------------- rel-pos bias expand: [16][64][64], pad = -1e30 ----------------
__global__ __launch_bounds__(256)
void bias_pre(const float* __restrict__ rel, float* __restrict__ bf) {
  int idx = blockIdx.x * 256 + threadIdx.x;  // 65536
  int head = idx >> 12, t1 = (idx >> 6) & 63, t2 = idx & 63;
  float v = -1e30f;
  if (t1 < 49 && t2 < 49) {
    int i1 = t1 / 7, j1 = t1 - i1 * 7, i2 = t2 / 7, j2 = t2 - i2 * 7;
    v = rel[((i1 - i2 + 6) * 13 + (j1 - j2 + 6)) * 16 + head];
  }
  bf[idx] = v;
}

// ---------------- LayerNorm (+optional shift+window gather) ----------------
template<bool WIN>
__global__ __launch_bounds__(128)
void ln_kernel(const float* __restrict__ in, const float* __restrict__ g,
               const float* __restrict__ be, bf16_t* __restrict__ out)
{
  const int r = blockIdx.x;           // output row (windowed if WIN)
  const int tid = threadIdx.x;
  long srow;
  if (WIN) {
    int bw = r / 49, t = r - bw * 49;
    int b = bw >> 6, w = bw & 63;
    int wh = w >> 3, ww = w & 7;
    int i = t / 7, j = t - i * 7;
    int hs = wh * 7 + i + 3; if (hs >= 56) hs -= 56;
    int wsr = ww * 7 + j + 3; if (wsr >= 56) wsr -= 56;
    srow = (long)b * 3136 + hs * 56 + wsr;
  } else {
    srow = r;
  }
  const float4 v = *(const float4*)(in + srow * 512 + tid * 4);
  float s = v.x + v.y + v.z + v.w;
  float sq = v.x * v.x + v.y * v.y + v.z * v.z + v.w * v.w;
#pragma unroll
  for (int m = 1; m < 64; m <<= 1) { s += __shfl_xor(s, m); sq += __shfl_xor(sq, m); }
  __shared__ float ls[2], lq[2];
  if ((tid & 63) == 0) { ls[tid >> 6] = s; lq[tid >> 6] = sq; }
  __syncthreads();
  s = ls[0] + ls[1]; sq = lq[0] + lq[1];
  const float mean = s * (1.f / 512.f);
  const float rs = rsqrtf(sq * (1.f / 512.f) - mean * mean + 1e-5f);
  const float4 gg = *(const float4*)(g + tid * 4);
  const float4 bb = *(const float4*)(be + tid * 4);
  ushort4 o;
  o.x = __builtin_bit_cast(uint16_t, f2b((v.x - mean) * rs * gg.x + bb.x));
  o.y = __builtin_bit_cast(uint16_t, f2b((v.y - mean) * rs * gg.y + bb.y));
  o.z = __builtin_bit_cast(uint16_t, f2b((v.z - mean) * rs * gg.z + bb.z));
  o.w = __builtin_bit_cast(uint16_t, f2b((v.w - mean) * rs * gg.w + bb.w));
  *(ushort4*)(out + (long)r * 512 + tid * 4) = o;
}

#define MFMA16(a, b, c) __builtin_amdgcn_mfma_f32_16x16x32_bf16((a), (b), (c), 0, 0, 0)

// Common epilogue address/value logic (verified: R5 passed with this helper)
template<int EPI>
DI void epi_store(int grow, int gcol, float v, const float* extra,
                  void* out0, void* out1v, void* out2v)
{
  long obase = 0;
  if (EPI == 0) {
    int bwi = grow / 49, t_ = grow - bwi * 49;
    obase = ((long)bwi * 784 + t_) * 32;
  } else if (EPI == 1) {
    int bwi = grow / 49, t_ = grow - bwi * 49;
    int b = bwi >> 6, w = bwi & 63;
    int wh = w >> 3, ww = w & 7;
    int i = t_ / 7, jj = t_ - i * 7;
    int hs = wh * 7 + i + 3; if (hs >= 56) hs -= 56;
    int wsr = ww * 7 + jj + 3; if (wsr >= 56) wsr -= 56;
    obase = ((long)b * 3136 + hs * 56 + wsr) * 512;
  } else if (EPI == 2) {
    obase = (long)grow * 2048;
  } else {
    obase = (long)grow * 512;
  }
  if (EPI == 0) {
    int part = gcol >> 9, head = (gcol >> 5) & 15, d = gcol & 31;
    if (part == 0) v *= SCALE;
    bf16_t* dst = (bf16_t*)(part == 0 ? out0 : (part == 1 ? out1v : out2v));
    dst[obase + (long)head * 1568 + d] = f2b(v);
  } else if (EPI == 1) {
    ((float*)out0)[obase + gcol] = v + extra[obase + gcol];
  } else if (EPI == 2) {
    float m2 = v * v;
    float z = v * fmaf(0.07135481627f, m2, 1.59576912161f);
    float e = __expf(z);
    float rr = __builtin_amdgcn_rcpf(e + 1.0f);
    ((bf16_t*)out0)[obase + gcol] = f2b(fmaf(-v, rr, v));
  } else {
    ((float*)out0)[obase + gcol] = v + extra[obase + gcol];
  }
}

// ---------------- persistent 256x256 GEMM, BK=32, 4-deep LDS pipeline ---------
// C[M,N] = A[M,K]*Bw[N,K]^T, M=100352 (392 bm-tiles), grid=256 (1/CU),
// 512 thr = 8 waves (2M x 4N), wave 128x64, acc[8][4].
// R6 change vs R3: BK 64->32, 4 step-buffers lds[4][A|B][16KB].  Stage step
// s+3 at step s into buf[(s+3)&3] = buf[(s-1)&3] (freed by end-of-step-(s-1)
// barrier).  vmcnt(8) at step end forces ONLY step s+1 landed -> steps
// s+2,s+3 = 96 KB/CU stay in flight (2x R3's 48 KB; Little's-law fix for the
// HBM-latency-bound staging rate).  Tail chain vmcnt 8->4->0.  FLOP/staged-
// byte unchanged at 131 (shape-determined, BK-independent).
// L2-coherent walk (R3, verified): XCD x owns bm in [49x,49x+49); block j
// has FIXED bn = j%NBN, walks bm = 49x + j/NBN + s*G, G = 32/NBN.
template<int EPI>
__global__ __launch_bounds__(512, 2)
void gemm256(const bf16_t* __restrict__ A, const bf16_t* __restrict__ Bw,
             const float* __restrict__ bias, const float* __restrict__ extra,
             void* __restrict__ out0, void* __restrict__ out1v, void* __restrict__ out2v,
             const int K, const int NBN)
{
  __shared__ __align__(128) bf16_t lds[4][2][8192];  // 128 KiB: [buf][A|B][256r x 32k]
  const int tid = threadIdx.x, lane = tid & 63, wave = tid >> 6;
  const int NT = K >> 5;                              // steps per tile (BK=32)

  const int xcd = blockIdx.x & 7, j = blockIdx.x >> 3;
  const int G = 32 / NBN;
  if (j >= G * NBN) return;               // idle only when NBN=6 (2 of 32)
  const int bmo = j / NBN;
  const int bn = j - bmo * NBN;           // fixed per block
  const int m0 = xcd * 49;
  const int tiles = (49 - bmo + G - 1) / G;
  const int ST = tiles * NT;

  // staging: thread covers rows (tid>>2), (tid>>2)+128; 16B slot tid&3;
  // source chunk = slot ^ ((row>>1)&3)  (proven 0-conflict XOR swizzle;
  // row+128 has the same swizzle).  LDS dest tid*16B is linear.
  const int srow = tid >> 2, slot = tid & 3;
  const int chunk = slot ^ ((srow >> 1) & 3);
  const size_t rowK = (size_t)128 * K;
  const size_t strideA = (size_t)G * 256 * K;

  const bf16_t* pAs = A + ((size_t)(m0 + bmo) * 256 + srow) * K + chunk * 8;
  const bf16_t* pBs = Bw + ((size_t)bn * 256 + srow) * K + chunk * 8;
  int sS = 0, ktS = 0;   // staged-step counter / within-tile step cursor

#define STG() do { \
    if (sS < ST) { \
      const int _b = sS & 3; \
      const bf16_t* _pa = pAs + ktS * 32; \
      const bf16_t* _pb = pBs + ktS * 32; \
      gld16(_pa, &lds[_b][0][tid * 8]); \
      gld16(_pa + rowK, &lds[_b][0][tid * 8 + 4096]); \
      gld16(_pb, &lds[_b][1][tid * 8]); \
      gld16(_pb + rowK, &lds[_b][1][tid * 8 + 4096]); \
      ++sS; if (++ktS == NT) { ktS = 0; pAs += strideA; } \
    } \
  } while (0)

  // fragment addressing: row stride 32 elems; chunk fkc of row R lives at
  // slot fkc ^ ((R>>1)&3); (R>>1)&3 == (fr>>1)&3 for every fragment row.
  const int fr = lane & 15, fkc = lane >> 4;
  const int wr = wave >> 2, wc = wave & 3;
  const int slotq = (fkc ^ ((fr >> 1) & 3)) << 3;
  const int aoff = (wr * 128 + fr) * 32 + slotq;  // + m*512
  const int boff = (wc * 64 + fr) * 32 + slotq;   // + n*512

  f32x4 acc[8][4] = {};

  // prologue: stage steps 0,1,2 (12 loads); force step 0 landed (<=8 left)
  STG(); STG(); STG();
  asm volatile("s_waitcnt vmcnt(8)");
  __builtin_amdgcn_s_barrier();
  __builtin_amdgcn_sched_barrier(0);

  int sG = 0;
  const int rq = fkc * 4;
  float bs[4];
#pragma unroll
  for (int n = 0; n < 4; ++n) bs[n] = bias[bn * 256 + wc * 64 + n * 16 + fr];

  for (int t = 0; t < tiles; ++t) {
    const int bmC = m0 + bmo + t * G;
#pragma unroll 4
    for (int kt = 0; kt < NT; ++kt) {
      const int b = kt & 3;   // == sG&3 since NT%4==0 (compile-time in unroll-4)
      bf16x8 af[8], bq[4];
#pragma unroll
      for (int m = 0; m < 8; ++m) af[m] = *(const bf16x8*)&lds[b][0][aoff + m * 512];
#pragma unroll
      for (int n = 0; n < 4; ++n) bq[n] = *(const bf16x8*)&lds[b][1][boff + n * 512];
      STG();                                   // stage step s+3 into buf[(s-1)&3]
      __builtin_amdgcn_sched_barrier(0);
      __builtin_amdgcn_s_barrier();
      asm volatile("s_waitcnt lgkmcnt(0)");
      __builtin_amdgcn_sched_barrier(0);
      __builtin_amdgcn_s_setprio(1);
#pragma unroll
      for (int m = 0; m < 8; ++m)
#pragma unroll
        for (int n = 0; n < 4; ++n)
          acc[m][n] = MFMA16(af[m], bq[n], acc[m][n]);
      __builtin_amdgcn_s_setprio(0);
      __builtin_amdgcn_sched_barrier(0);
      // end-of-step wait: force step s+1 landed; keep s+2,s+3 (96 KB) flying
      if (sG + 4 <= ST)      asm volatile("s_waitcnt vmcnt(8)");
      else if (sG + 3 == ST) asm volatile("s_waitcnt vmcnt(4)");
      else                   asm volatile("s_waitcnt vmcnt(0)");
      __builtin_amdgcn_s_barrier();
      __builtin_amdgcn_sched_barrier(0);
      ++sG;
    }
    // ---- per-tile epilogue (no LDS; staging keeps flying; stores only make
    //      the next steps' vmcnt waits stricter -- safe direction) ----
#pragma unroll
    for (int m = 0; m < 8; ++m)
#pragma unroll
      for (int jj = 0; jj < 4; ++jj) {
        const int grow = bmC * 256 + wr * 128 + m * 16 + rq + jj;
#pragma unroll
        for (int n = 0; n < 4; ++n) {
          const int gcol = bn * 256 + wc * 64 + n * 16 + fr;
          epi_store<EPI>(grow, gcol, acc[m][n][jj] + bs[n], extra, out0, out1v, out2v);
        }
      }
#pragma unroll
    for (int m = 0; m < 8; ++m)
#pragma unroll
      for (int n = 0; n < 4; ++n) acc[m][n] = (f32x4){0.f, 0.f, 0.f, 0.f};
  }
#undef STG
}

// ---------------- attention: one block per (window, head) ----------------
__global__ __launch_bounds__(256)
void attn_kernel(const bf16_t* __restrict__ qb, const bf16_t* __restrict__ kb,
                 const bf16_t* __restrict__ vb, const float* __restrict__ biasf,
                 bf16_t* __restrict__ aout)
{
  __shared__ bf16_t Q[64 * 32];
  __shared__ bf16_t Kl[64 * 32];
  __shared__ bf16_t Vt[32 * 64];
  __shared__ bf16_t Pl[4][16 * 64];
  const int bid = blockIdx.x;
  const int bw = bid >> 4, head = bid & 15;
  const int tid = threadIdx.x, lane = tid & 63, wave = tid >> 6;
  {
    uint4 z = {0u, 0u, 0u, 0u};
    *(uint4*)&Q[tid * 8] = z;
    *(uint4*)&Kl[tid * 8] = z;
    *(uint4*)&Vt[tid * 8] = z;
  }
  __syncthreads();
  const bf16_t* qsrc = qb + (long)bid * (49 * 32);
  const bf16_t* ksrc = kb + (long)bid * (49 * 32);
  const bf16_t* vsrc = vb + (long)bid * (49 * 32);
  if (tid < 196) {
    *(uint4*)&Q[tid * 8] = *(const uint4*)(qsrc + tid * 8);
    *(uint4*)&Kl[tid * 8] = *(const uint4*)(ksrc + tid * 8);
  }
  for (int e = tid; e < 1568; e += 256) {
    int t = e >> 5, d = e & 31;
    Vt[d * 64 + t] = vsrc[e];
  }
  __syncthreads();
  const int fr = lane & 15, fk = (lane >> 4) * 8, rq = (lane >> 4) * 4;
  bf16x8 aq = *(const bf16x8*)&Q[(wave * 16 + fr) * 32 + fk];
  f32x4 s[4];
#pragma unroll
  for (int n = 0; n < 4; ++n) {
    bf16x8 bk = *(const bf16x8*)&Kl[(n * 16 + fr) * 32 + fk];
    f32x4 z = {0.f, 0.f, 0.f, 0.f};
    s[n] = __builtin_amdgcn_mfma_f32_16x16x32_bf16(aq, bk, z, 0, 0, 0);
  }
  const int w = bw & 63;
  const bool wh7 = ((w >> 3) == 7), ww7 = ((w & 7) == 7);
  const float* bh = biasf + head * 4096;
#pragma unroll
  for (int j = 0; j < 4; ++j) {
    const int row = wave * 16 + rq + j;  // t1 in [0,64)
    int i1 = row / 7, j1 = row - i1 * 7;
    bool b1h = wh7 && (i1 >= 4), b1w = ww7 && (j1 >= 4);
    float pv[4];
    float mx = -3.0e38f;
#pragma unroll
    for (int n = 0; n < 4; ++n) {
      const int col = n * 16 + fr;
      float v = s[n][j] + bh[row * 64 + col];
      if (wh7 || ww7) {
        int i2 = col / 7, j2 = col - i2 * 7;
        bool b2h = wh7 && (i2 >= 4), b2w = ww7 && (j2 >= 4);
        if ((b1h != b2h) || (b1w != b2w)) v -= 100.f;
      }
      pv[n] = v;
      mx = fmaxf(mx, v);
    }
#pragma unroll
    for (int msk = 1; msk < 16; msk <<= 1) mx = fmaxf(mx, __shfl_xor(mx, msk));
    float sm = 0.f;
#pragma unroll
    for (int n = 0; n < 4; ++n) { pv[n] = __expf(pv[n] - mx); sm += pv[n]; }
#pragma unroll
    for (int msk = 1; msk < 16; msk <<= 1) sm += __shfl_xor(sm, msk);
    const float inv = 1.f / sm;
#pragma unroll
    for (int n = 0; n < 4; ++n)
      Pl[wave][(rq + j) * 64 + n * 16 + fr] = f2b(pv[n] * inv);
  }
  __syncthreads();
  f32x4 o[2] = {};
#pragma unroll
  for (int kk = 0; kk < 2; ++kk) {
    bf16x8 pa = *(const bf16x8*)&Pl[wave][fr * 64 + kk * 32 + fk];
#pragma unroll
    for (int dt = 0; dt < 2; ++dt) {
      bf16x8 vv = *(const bf16x8*)&Vt[(dt * 16 + fr) * 64 + kk * 32 + fk];
      o[dt] = __builtin_amdgcn_mfma_f32_16x16x32_bf16(pa, vv, o[dt], 0, 0, 0);
    }
  }
#pragma unroll
  for (int j = 0; j < 4; ++j) {
    const int t1 = wave * 16 + rq + j;
    if (t1 < 49) {
      bf16_t* dst = aout + ((long)bw * 49 + t1) * 512 + head * 32;
      dst[fr] = f2b(o[0][j]);
      dst[16 + fr] = f2b(o[1][j]);
    }
  }
}

// ---------------- launch ----------------
extern "C" void kernel_launch(void* const* d_in, const int* in_sizes, int n_in,
                              void* d_out, int out_size, void* d_ws, size_t ws_size,
                              hipStream_t stream)
{
  const float* x      = (const float*)d_in[0];
  const float* n1g    = (const float*)d_in[1];
  const float* n1b    = (const float*)d_in[2];
  const float* qkv_w  = (const float*)d_in[3];
  const float* qkv_b  = (const float*)d_in[4];
  const float* rel    = (const float*)d_in[5];
  const float* proj_w = (const float*)d_in[6];
  const float* proj_b = (const float*)d_in[7];
  const float* n2g    = (const float*)d_in[8];
  const float* n2b    = (const float*)d_in[9];
  const float* w1     = (const float*)d_in[10];
  const float* b1     = (const float*)d_in[11];
  const float* w2     = (const float*)d_in[12];
  const float* b2     = (const float*)d_in[13];

  char* ws = (char*)d_ws;
  bf16_t* Wqkv  = (bf16_t*)(ws + 0);          // 1536*512*2 = 1572864
  bf16_t* Wproj = (bf16_t*)(ws + 1572864);    // 512*512*2  = 524288
  bf16_t* Wm1   = (bf16_t*)(ws + 2097152);    // 2048*512*2 = 2097152
  bf16_t* Wm2   = (bf16_t*)(ws + 4194304);    // 512*2048*2 = 2097152
  float*  biasf = (float*)(ws + 6291456);     // 16*64*64*4 = 1048576
  const size_t ABYTES = (size_t)100352 * 512 * 2;  // 102760448
  const size_t P1 = 8388608;
  const size_t P2 = P1 + ABYTES + 1048576;         // 112197632
  bf16_t* xw      = (bf16_t*)(ws + P1);
  bf16_t* qbuf    = (bf16_t*)(ws + P2);
  bf16_t* kbuf    = (bf16_t*)(ws + P2 + ABYTES);
  bf16_t* vbuf    = (bf16_t*)(ws + P2 + 2 * ABYTES);
  bf16_t* attnout = xw;       // reuse after QKV gemm consumed xw
  bf16_t* h2      = xw;       // reuse after proj consumed attnout
  bf16_t* hidden  = qbuf;     // reuse q/k/v (+spare) after attention

  cvtw<<<768, 256, 0, stream>>>(qkv_w, Wqkv, 1536 * 512);
  cvtw<<<256, 256, 0, stream>>>(proj_w, Wproj, 512 * 512);
  cvtw<<<1024, 256, 0, stream>>>(w1, Wm1, 2048 * 512);
  cvtw<<<1024, 256, 0, stream>>>(w2, Wm2, 512 * 2048);
  bias_pre<<<256, 256, 0, stream>>>(rel, biasf);

  ln_kernel<true><<<100352, 128, 0, stream>>>(x, n1g, n1b, xw);
  gemm256<0><<<256, 512, 0, stream>>>(xw, Wqkv, qkv_b, nullptr,
                                      qbuf, kbuf, vbuf, 512, 6);
  attn_kernel<<<32768, 256, 0, stream>>>(qbuf, kbuf, vbuf, biasf, attnout);
  gemm256<1><<<256, 512, 0, stream>>>(attnout, Wproj, proj_b, x,
                                      d_out, nullptr, nullptr, 512, 2);
  ln_kernel<false><<<100352, 128, 0, stream>>>((const float*)d_out, n2g, n2b, h2);
  gemm256<2><<<256, 512, 0, stream>>>(h2, Wm1, b1, nullptr,
                                      hidden, nullptr, nullptr, 512, 8);
  gemm256<3><<<256, 512, 0, stream>>>(hidden, Wm2, b2, (const float*)d_out,
                                      d_out, nullptr, nullptr, 2048, 2);
}